// Round 12
// baseline (468.610 us; speedup 1.0000x reference)
//
#include <hip/hip_runtime.h>
#include <hip/hip_bf16.h>
#include <cstdint>
#include <math.h>

#define EMBED 1024
#define HEADS 16
#define HDIM 64
#define SEQ 2048
#define TOKENS 8192   // 4*2048

typedef __attribute__((ext_vector_type(8))) short short8;
typedef __attribute__((ext_vector_type(4))) float f32x4;
typedef __attribute__((ext_vector_type(2))) unsigned int uint2v;
typedef unsigned short ushort_t;

__device__ __forceinline__ float bf2f(ushort_t u) {
  union { unsigned int i; float f; } c; c.i = ((unsigned int)u) << 16; return c.f;
}
__device__ __forceinline__ ushort_t f2bf(float f) {
  union { float f; unsigned int i; } c; c.f = f;
  unsigned int x = c.i;
  unsigned int r = x + 0x7fffu + ((x >> 16) & 1u);  // RNE
  return (ushort_t)(r >> 16);
}
// pack two f32 -> two bf16 (round-half-up) in one dword: {hi=b, lo=a}
__device__ __forceinline__ unsigned int pack_bf16_rhu(float a, float b) {
  unsigned int ua = __float_as_uint(a) + 0x8000u;
  unsigned int ub = __float_as_uint(b) + 0x8000u;
  return __builtin_amdgcn_perm(ub, ua, 0x07060302u);
}
// single-instruction packed cvt (RNE): dst.lo = bf16(lo), dst.hi = bf16(hi)
__device__ __forceinline__ unsigned int cvt_pk_bf16(float lo, float hi) {
  unsigned int r;
  asm("v_cvt_pk_bf16_f32 %0, %1, %2" : "=v"(r) : "v"(lo), "v"(hi));
  return r;
}
__device__ __forceinline__ void g2lds16(const void* g, void* l) {
  __builtin_amdgcn_global_load_lds(
      (const __attribute__((address_space(1))) unsigned int*)g,
      (__attribute__((address_space(3))) unsigned int*)l, 16, 0, 0);
}
// exact-GELU via branchless A&S 7.1.26 erf (|eps|<=1.5e-7, way below bf16 ulp)
__device__ __forceinline__ float gelu_fast(float v) {
  float x = v * 0.70710678118654752f;          // v/sqrt(2)
  float ax = fabsf(x);
  float t = __builtin_amdgcn_rcpf(__builtin_fmaf(0.3275911f, ax, 1.0f));
  float p = __builtin_fmaf(1.061405429f, t, -1.453152027f);
  p = __builtin_fmaf(p, t, 1.421413741f);
  p = __builtin_fmaf(p, t, -0.284496736f);
  p = __builtin_fmaf(p, t, 0.254829592f);
  p = p * t;
  float e = __builtin_amdgcn_exp2f(-ax * ax * 1.4426950408889634f);
  float erfax = __builtin_fmaf(-p, e, 1.0f);   // erf(|x|)
  float erfx = copysignf(erfax, x);
  return 0.5f * v * (1.0f + erfx);
}

// ---------- prep: transpose + cast f32 -> bf16: out[c][r] = bf16(in[r][c]) --
__global__ __launch_bounds__(256) void transpose_cast_k(const float* __restrict__ in,
                                                        ushort_t* __restrict__ out,
                                                        int R, int C) {
  __shared__ ushort_t tile[32][33];
  int tx = threadIdx.x & 31, ty = threadIdx.x >> 5;
  int c0 = blockIdx.x * 32, r0 = blockIdx.y * 32;
#pragma unroll
  for (int i = ty; i < 32; i += 8)
    tile[i][tx] = f2bf(in[(long)(r0 + i) * C + (c0 + tx)]);
  __syncthreads();
#pragma unroll
  for (int i = ty; i < 32; i += 8) out[(long)(c0 + i) * R + (r0 + tx)] = tile[tx][i];
}

// ---------- layernorm rows of 1024, f32 in -> bf16 out ----------
// Output packed via v_cvt_pk_bf16_f32 (RNE, bit-identical to f2bf) into a
// single 8B store per thread (verified round 11, part of the 457.9us best).
__global__ __launch_bounds__(256) void ln_k(const float* __restrict__ xin,
                                            const float* __restrict__ g,
                                            const float* __restrict__ b,
                                            ushort_t* __restrict__ out) {
  int row = blockIdx.x, t = threadIdx.x;
  long base = (long)row * EMBED + t * 4;
  f32x4 xv = *(const f32x4*)(xin + base);
  float v[4] = {xv[0], xv[1], xv[2], xv[3]};
  float s1 = v[0] + v[1] + v[2] + v[3];
  float s2 = v[0]*v[0] + v[1]*v[1] + v[2]*v[2] + v[3]*v[3];
#pragma unroll
  for (int m = 1; m < 64; m <<= 1) { s1 += __shfl_xor(s1, m, 64); s2 += __shfl_xor(s2, m, 64); }
  __shared__ float ws1[4], ws2[4];
  int w = t >> 6, lane = t & 63;
  if (lane == 0) { ws1[w] = s1; ws2[w] = s2; }
  __syncthreads();
  float S1 = ws1[0] + ws1[1] + ws1[2] + ws1[3];
  float S2 = ws2[0] + ws2[1] + ws2[2] + ws2[3];
  float mean = S1 * (1.0f / EMBED);
  float var = S2 * (1.0f / EMBED) - mean * mean;
  float rstd = rsqrtf(var + 1e-5f);
  int c = t * 4;
  float y0 = (v[0] - mean) * rstd * g[c + 0] + b[c + 0];
  float y1 = (v[1] - mean) * rstd * g[c + 1] + b[c + 1];
  float y2 = (v[2] - mean) * rstd * g[c + 2] + b[c + 2];
  float y3 = (v[3] - mean) * rstd * g[c + 3] + b[c + 3];
  uint2v d;
  d[0] = cvt_pk_bf16(y0, y1);
  d[1] = cvt_pk_bf16(y2, y3);
  *(uint2v*)(out + (long)row * EMBED + c) = d;
}

// ---------------- fused QKV: [131072,64] x (64x64)^T x3 ----------------
// Q output is pre-scaled by log2(e)/sqrt(EMBED) so attention works directly in
// the exp2 domain. A-tile LDS is XOR-swizzled (chunk ^= row&7) via pre-swizzled
// global source (rule #21): linear g2lds dest + swizzled ds_read.
__global__ __launch_bounds__(256) void qkv_k(const ushort_t* __restrict__ xn,
                                             const ushort_t* __restrict__ WqT,
                                             const ushort_t* __restrict__ WkT,
                                             const ushort_t* __restrict__ WvT,
                                             ushort_t* __restrict__ q, ushort_t* __restrict__ k,
                                             ushort_t* __restrict__ v) {
  __shared__ __align__(16) ushort_t As[128 * 64];  // 16KB
  int t = threadIdx.x;
  long rowbase = (long)blockIdx.x * 128;
#pragma unroll
  for (int p = 0; p < 4; ++p) {
    int idx = p * 256 + t;             // 1024 chunks of 16B
    int row = idx >> 3, chunk = idx & 7;
    int sc = chunk ^ (row & 7);
    g2lds16(xn + (rowbase + row) * 64 + sc * 8, As + idx * 8);
  }
  __syncthreads();
  int w = t >> 6, lane = t & 63, l15 = lane & 15, quad = lane >> 4;
  short8 af[2][2];
#pragma unroll
  for (int mi = 0; mi < 2; ++mi)
#pragma unroll
    for (int ks = 0; ks < 2; ++ks) {
      int row = w * 32 + mi * 16 + l15;
      int ch = (ks * 4 + quad) ^ (row & 7);
      af[mi][ks] = *(const short8*)(As + row * 64 + ch * 8);
    }
  const ushort_t* Ws[3] = {WqT, WkT, WvT};
  ushort_t* Os[3] = {q, k, v};
#pragma unroll
  for (int wsel = 0; wsel < 3; ++wsel) {
    const ushort_t* W = Ws[wsel];
    float oscale = (wsel == 0) ? 0.0450842200277801f : 1.0f;  // log2e/32 : 1
    short8 bfr[4][2];
#pragma unroll
    for (int ni = 0; ni < 4; ++ni)
#pragma unroll
      for (int ks = 0; ks < 2; ++ks)
        bfr[ni][ks] = *(const short8*)(W + (ni * 16 + l15) * 64 + ks * 32 + quad * 8);
    f32x4 acc[2][4] = {};
#pragma unroll
    for (int mi = 0; mi < 2; ++mi)
#pragma unroll
      for (int ni = 0; ni < 4; ++ni)
#pragma unroll
        for (int ks = 0; ks < 2; ++ks)
          acc[mi][ni] = __builtin_amdgcn_mfma_f32_16x16x32_bf16(af[mi][ks], bfr[ni][ks],
                                                                acc[mi][ni], 0, 0, 0);
    ushort_t* O = Os[wsel];
#pragma unroll
    for (int mi = 0; mi < 2; ++mi)
#pragma unroll
      for (int ni = 0; ni < 4; ++ni)
#pragma unroll
        for (int r = 0; r < 4; ++r) {
          long rg = rowbase + w * 32 + mi * 16 + quad * 4 + r;
          O[rg * 64 + ni * 16 + l15] = f2bf(acc[mi][ni][r] * oscale);
        }
  }
}

// ---------------- flash attention: grid (16 qtiles, 64 batch-heads) ---------
// Round-5/7 structure (measured 105.1-106.7 five times). LOCAL OPTIMUM —
// do not restructure.
#define KSTR 72
__global__ __launch_bounds__(256, 4) void attn_k(const ushort_t* __restrict__ q,
                                                 const ushort_t* __restrict__ kk,
                                                 const ushort_t* __restrict__ vv,
                                                 ushort_t* __restrict__ ctx) {
  __shared__ __align__(16) ushort_t sm[64 * KSTR * 2];
  ushort_t* Ks = sm;                    // [key][KSTR]
  ushort_t* Vt = sm + 64 * KSTR;        // [d][KSTR], key-permuted columns
  int t = threadIdx.x;
  int nb = gridDim.x * gridDim.y;                      // 1024, %8==0
  int bid = blockIdx.x + gridDim.x * blockIdx.y;
  int swz = (bid & 7) * (nb >> 3) + (bid >> 3);
  int qt = swz & (gridDim.x - 1), bh = swz / gridDim.x;
  int n = bh >> 4, h = bh & 15;
  long qtok0 = (long)n * SEQ + qt * 128;
  int w = t >> 6, lane = t & 63, l15 = lane & 15, quad = lane >> 4;
  short8 qf[2][2];
#pragma unroll
  for (int g = 0; g < 2; ++g)
#pragma unroll
    for (int ks = 0; ks < 2; ++ks)
      qf[g][ks] = *(const short8*)(q + (qtok0 + w * 32 + g * 16 + l15) * EMBED +
                                   h * HDIM + ks * 32 + quad * 8);
  short8 ones;
#pragma unroll
  for (int j = 0; j < 8; ++j) ones[j] = (short)0x3F80;  // bf16 1.0
  int vkey = t & 63;
  int vcol = (vkey & 32) | ((vkey & 12) << 1) | ((vkey & 16) >> 2) | (vkey & 3);
  const ushort_t* kp = kk + ((long)n * SEQ + (t >> 3)) * EMBED + h * HDIM + (t & 7) * 8;
  const ushort_t* vp = vv + ((long)n * SEQ + vkey) * EMBED + h * HDIM + w * 8;
  float m_run[2] = {-1e30f, -1e30f}, l_run[2] = {0.f, 0.f};
  f32x4 acc_o[2][4] = {};   // O^T per group: d = nf*16+quad*4+r, q = l15
  for (int kt = 0; kt < SEQ / 64; ++kt) {
    short8 kreg[2];
#pragma unroll
    for (int p = 0; p < 2; ++p) kreg[p] = *(const short8*)(kp + (long)p * 32 * EMBED);
    short8 vreg[2];
#pragma unroll
    for (int p = 0; p < 2; ++p) vreg[p] = *(const short8*)(vp + p * 32);
    kp += 64 * EMBED;
    vp += 64 * EMBED;
    __syncthreads();  // previous tile's readers done
#pragma unroll
    for (int p = 0; p < 2; ++p) {
      int idx = p * 256 + t;
      int key = idx >> 3, chunk = idx & 7;
      *(short8*)(Ks + key * KSTR + chunk * 8) = kreg[p];
    }
#pragma unroll
    for (int p = 0; p < 2; ++p) {
      int c = p * 4 + w;
#pragma unroll
      for (int j = 0; j < 8; ++j) Vt[(c * 8 + j) * KSTR + vcol] = (ushort_t)vreg[p][j];
    }
    __syncthreads();
    // S^T[key][q] = mfma(A=K, B=Q): K fragments shared by both q-groups
    f32x4 st[2][4] = {};
#pragma unroll
    for (int ks = 0; ks < 2; ++ks)
#pragma unroll
      for (int nf = 0; nf < 4; ++nf) {
        short8 kf = *(const short8*)(Ks + (nf * 16 + l15) * KSTR + ks * 32 + quad * 8);
        st[0][nf] = __builtin_amdgcn_mfma_f32_16x16x32_bf16(kf, qf[0][ks], st[0][nf], 0, 0, 0);
        st[1][nf] = __builtin_amdgcn_mfma_f32_16x16x32_bf16(kf, qf[1][ks], st[1][nf], 0, 0, 0);
      }
    unsigned int Dk[2][4][2];
    float alpha[2];
#pragma unroll
    for (int g = 0; g < 2; ++g) {
      float mx = fmaxf(fmaxf(st[g][0][0], st[g][0][1]), fmaxf(st[g][0][2], st[g][0][3]));
#pragma unroll
      for (int nf = 1; nf < 4; ++nf)
        mx = fmaxf(mx, fmaxf(fmaxf(st[g][nf][0], st[g][nf][1]),
                             fmaxf(st[g][nf][2], st[g][nf][3])));
      mx = fmaxf(mx, __shfl_xor(mx, 16, 64));
      mx = fmaxf(mx, __shfl_xor(mx, 32, 64));
      float mold = m_run[g];
      int skip = __all(mx - mold <= 8.0f);
      float mnew = skip ? mold : fmaxf(mold, mx);
      alpha[g] = skip ? 1.0f : __builtin_amdgcn_exp2f(mold - mnew);
      m_run[g] = mnew;
#pragma unroll
      for (int nf = 0; nf < 4; ++nf) {
#pragma unroll
        for (int r = 0; r < 4; ++r)
          st[g][nf][r] = __builtin_amdgcn_exp2f(st[g][nf][r] - mnew);
        Dk[g][nf][0] = cvt_pk_bf16(st[g][nf][0], st[g][nf][1]);
        Dk[g][nf][1] = cvt_pk_bf16(st[g][nf][2], st[g][nf][3]);
      }
      if (!skip) {
#pragma unroll
        for (int nf = 0; nf < 4; ++nf)
#pragma unroll
          for (int r = 0; r < 4; ++r) acc_o[g][nf][r] *= alpha[g];
      }
    }
    f32x4 ts[2] = {};
#pragma unroll
    for (int ks = 0; ks < 2; ++ks) {
      union { unsigned int u[4]; short8 s8; } pf0, pf1;
      pf0.u[0] = Dk[0][2 * ks][0];     pf0.u[1] = Dk[0][2 * ks][1];
      pf0.u[2] = Dk[0][2 * ks + 1][0]; pf0.u[3] = Dk[0][2 * ks + 1][1];
      pf1.u[0] = Dk[1][2 * ks][0];     pf1.u[1] = Dk[1][2 * ks][1];
      pf1.u[2] = Dk[1][2 * ks + 1][0]; pf1.u[3] = Dk[1][2 * ks + 1][1];
      ts[0] = __builtin_amdgcn_mfma_f32_16x16x32_bf16(ones, pf0.s8, ts[0], 0, 0, 0);
      ts[1] = __builtin_amdgcn_mfma_f32_16x16x32_bf16(ones, pf1.s8, ts[1], 0, 0, 0);
#pragma unroll
      for (int nf = 0; nf < 4; ++nf) {
        short8 vf = *(const short8*)(Vt + (nf * 16 + l15) * KSTR + ks * 32 + quad * 8);
        acc_o[0][nf] = __builtin_amdgcn_mfma_f32_16x16x32_bf16(vf, pf0.s8, acc_o[0][nf], 0, 0, 0);
        acc_o[1][nf] = __builtin_amdgcn_mfma_f32_16x16x32_bf16(vf, pf1.s8, acc_o[1][nf], 0, 0, 0);
      }
    }
    l_run[0] = l_run[0] * alpha[0] + ts[0][0];
    l_run[1] = l_run[1] * alpha[1] + ts[1][0];
  }
#pragma unroll
  for (int g = 0; g < 2; ++g) {
    float inv_l = 1.0f / fmaxf(l_run[g], 1e-30f);
    long tok = qtok0 + w * 32 + g * 16 + l15;
#pragma unroll
    for (int nf = 0; nf < 4; ++nf) {
      unsigned int d0 = pack_bf16_rhu(acc_o[g][nf][0] * inv_l, acc_o[g][nf][1] * inv_l);
      unsigned int d1 = pack_bf16_rhu(acc_o[g][nf][2] * inv_l, acc_o[g][nf][3] * inv_l);
      unsigned int* dst = (unsigned int*)(ctx + tok * EMBED + h * HDIM + nf * 16 + quad * 4);
      dst[0] = d0;
      dst[1] = d1;
    }
  }
}

// ---------------- gemm_res256: 256x128, BK=64, 8-wave deep pipeline ---------
// Verified round 9. XCD mapping now 8(M)x4(N) per XCD so W2's B working set
// (4 panels x 1MB @ K=4096) fits the 4MB per-XCD L2.
__global__ __launch_bounds__(512, 2) void gemm_res256(const ushort_t* __restrict__ A,
                                                      const ushort_t* __restrict__ BT,
                                                      const float* __restrict__ bias,
                                                      const float* __restrict__ res,
                                                      float* __restrict__ out_f,
                                                      int M, int N, int K) {
  __shared__ __align__(16) ushort_t As[2][256 * 64];   // 64KB
  __shared__ __align__(16) ushort_t Bs[2][128 * 64];   // 32KB
  int t = threadIdx.x;
  int nbx = gridDim.x;                 // 8 N-tiles
  int bid = blockIdx.x + nbx * blockIdx.y;   // 0..255
  // XCD-tiled mapping: grid (32 M x 8 N) split into 4x2 regions of 8M x 4N,
  // one region per XCD (bid&7 ~ XCD). B per XCD = 4 panels (<= 4MB L2).
  int xcd = bid & 7, l = bid >> 3;     // l in 0..31
  int by = (xcd >> 1) * 8 + (l >> 2);
  int bx = (xcd & 1) * 4 + (l & 3);
  long m0 = (long)by * 256;
  long n0 = (long)bx * 128;
  int w = t >> 6, lane = t & 63, l15 = lane & 15, quad = lane >> 4;
  int wm = w >> 2, wn = w & 3;         // 2 x 4 wave grid, 128x32 per wave
  int r0 = t >> 3;                     // 0..63
  int sc = (t & 7) ^ (r0 & 7);         // p*64 ≡ 0 mod 8 -> p-invariant
  const ushort_t* ap = A + (m0 + r0) * (long)K + sc * 8;
  const ushort_t* bp = BT + (n0 + r0) * (long)K + sc * 8;
  long pstride = (long)64 * K;
  int NT = K >> 6;
  auto stage = [&](int kt, int buf) {
    const ushort_t* a = ap + (long)kt * 64;
    const ushort_t* b = bp + (long)kt * 64;
#pragma unroll
    for (int p = 0; p < 4; ++p)        // A: 256 rows = 4 passes of 64
      g2lds16(a + p * pstride, As[buf] + (p * 512 + t) * 8);
#pragma unroll
    for (int p = 0; p < 2; ++p)        // B: 128 rows = 2 passes of 64
      g2lds16(b + p * pstride, Bs[buf] + (p * 512 + t) * 8);
  };
  unsigned cb = (unsigned)((quad ^ (l15 & 7)) * 16);
  unsigned aoff = (unsigned)((wm * 128 + l15) * 128) + cb;
  unsigned boff = (unsigned)((wn * 32 + l15) * 128) + cb;
  f32x4 acc[8][2] = {};
  stage(0, 0);
  stage(1, 1);
  for (int kt = 0; kt < NT; ++kt) {
    if (kt + 1 < NT) {
      asm volatile("s_waitcnt vmcnt(6)" ::: "memory");   // tile kt's 6 landed
    } else {
      asm volatile("s_waitcnt vmcnt(0)" ::: "memory");   // final drain
    }
    __builtin_amdgcn_s_barrier();                        // bar1
    const char* Asb = (const char*)As[kt & 1];
    const char* Bsb = (const char*)Bs[kt & 1];
    {  // ks = 0
      const char* Ab = Asb + aoff;
      const char* Bb = Bsb + boff;
      short8 af[8], bfr[2];
#pragma unroll
      for (int mi = 0; mi < 8; ++mi) af[mi] = *(const short8*)(Ab + mi * 2048);
#pragma unroll
      for (int ni = 0; ni < 2; ++ni) bfr[ni] = *(const short8*)(Bb + ni * 2048);
      __builtin_amdgcn_s_setprio(1);
#pragma unroll
      for (int mi = 0; mi < 8; ++mi)
#pragma unroll
        for (int ni = 0; ni < 2; ++ni)
          acc[mi][ni] =
              __builtin_amdgcn_mfma_f32_16x16x32_bf16(af[mi], bfr[ni], acc[mi][ni], 0, 0, 0);
      __builtin_amdgcn_s_setprio(0);
    }
    {  // ks = 1
      const char* Ab = Asb + (aoff ^ 64u);
      const char* Bb = Bsb + (boff ^ 64u);
      short8 af[8], bfr[2];
#pragma unroll
      for (int mi = 0; mi < 8; ++mi) af[mi] = *(const short8*)(Ab + mi * 2048);
#pragma unroll
      for (int ni = 0; ni < 2; ++ni) bfr[ni] = *(const short8*)(Bb + ni * 2048);
      asm volatile("s_waitcnt lgkmcnt(0)" ::: "memory"); // this wave's reads done
      __builtin_amdgcn_s_barrier();                      // bar2: ALL waves done
      __builtin_amdgcn_sched_barrier(0);                 // pin: no motion across
      if (kt + 2 < NT) stage(kt + 2, kt & 1);            // restage just-read buf
      __builtin_amdgcn_s_setprio(1);
#pragma unroll
      for (int mi = 0; mi < 8; ++mi)
#pragma unroll
        for (int ni = 0; ni < 2; ++ni)
          acc[mi][ni] =
              __builtin_amdgcn_mfma_f32_16x16x32_bf16(af[mi], bfr[ni], acc[mi][ni], 0, 0, 0);
      __builtin_amdgcn_s_setprio(0);
    }
  }
  // epilogue: acc + bias + res -> f32
#pragma unroll
  for (int mi = 0; mi < 8; ++mi)
#pragma unroll
    for (int ni = 0; ni < 2; ++ni) {
      long col = n0 + wn * 32 + ni * 16 + l15;
      float bv = bias[col];
#pragma unroll
      for (int r = 0; r < 4; ++r) {
        long row = m0 + wm * 128 + mi * 16 + quad * 4 + r;
        long off = row * (long)N + col;
        out_f[off] = acc[mi][ni][r] + bv + res[off];
      }
    }
}

// ---------------- gemm_ff1: 256x256, BK=64, 8-wave deep pipeline ------------
// Round-7 coarse 2-block schedule (verified). XCD mapping now 8(M)x8(N) per
// XCD: B per XCD = 8 panels = 4.0MB (fits per-XCD L2), and both 256-block
// residency waves reuse the SAME B panels (was: 16 panels = 8.4MB, thrash ->
// 74MB FETCH profiled in round 11).
__global__ __launch_bounds__(512, 2) void gemm_ff1(const ushort_t* __restrict__ A,
                                                   const ushort_t* __restrict__ BT,
                                                   const float* __restrict__ bias,
                                                   ushort_t* __restrict__ out_bf,
                                                   int M, int N, int K) {
  __shared__ __align__(16) ushort_t As[2][256 * 64];   // 64KB
  __shared__ __align__(16) ushort_t Bs[2][256 * 64];   // 64KB
  int t = threadIdx.x;
  int nbx = gridDim.x;                 // 16 N-tiles
  int bid = blockIdx.x + nbx * blockIdx.y;   // 0..511
  // XCD-tiled mapping: grid (32 M x 16 N) split into 4x2 regions of 8M x 8N,
  // one region per XCD (bid&7 ~ XCD).
  int xcd = bid & 7, l = bid >> 3;     // l in 0..63
  int by = (xcd >> 1) * 8 + (l >> 3);
  int bx = (xcd & 1) * 8 + (l & 7);
  long m0 = (long)by * 256;
  long n0 = (long)bx * 256;
  int w = t >> 6, lane = t & 63, l15 = lane & 15, quad = lane >> 4;
  int wm = w >> 2, wn = w & 3;         // 2 x 4 wave grid, 128x64 per wave
  int r0 = t >> 3;                     // 0..63
  int sc = (t & 7) ^ (r0 & 7);         // p*64 ≡ 0 mod 8 -> p-invariant
  const ushort_t* ap = A + (m0 + r0) * (long)K + sc * 8;
  const ushort_t* bp = BT + (n0 + r0) * (long)K + sc * 8;
  long pstride = (long)64 * K;
  int NT = K >> 6;                     // 16
  auto stage = [&](int kt, int buf) {
    const ushort_t* a = ap + (long)kt * 64;
    const ushort_t* b = bp + (long)kt * 64;
#pragma unroll
    for (int p = 0; p < 4; ++p) {
      g2lds16(a + p * pstride, As[buf] + (p * 512 + t) * 8);
      g2lds16(b + p * pstride, Bs[buf] + (p * 512 + t) * 8);
    }
  };
  unsigned cb = (unsigned)((quad ^ (l15 & 7)) * 16);
  unsigned aoff = (unsigned)((wm * 128 + l15) * 128) + cb;
  unsigned boff = (unsigned)((wn * 64 + l15) * 128) + cb;
  f32x4 acc[8][4] = {};
  stage(0, 0);
  stage(1, 1);
  for (int kt = 0; kt < NT; ++kt) {
    if (kt + 1 < NT) {
      asm volatile("s_waitcnt vmcnt(8)" ::: "memory");   // tile kt landed
    } else {
      asm volatile("s_waitcnt vmcnt(0)" ::: "memory");   // final drain
    }
    __builtin_amdgcn_s_barrier();                        // bar1
    const char* Asb = (const char*)As[kt & 1];
    const char* Bsb = (const char*)Bs[kt & 1];
    {  // ks = 0
      const char* Ab = Asb + aoff;
      const char* Bb = Bsb + boff;
      short8 af[8], bfr[4];
#pragma unroll
      for (int mi = 0; mi < 8; ++mi) af[mi] = *(const short8*)(Ab + mi * 2048);
#pragma unroll
      for (int ni = 0; ni < 4; ++ni) bfr[ni] = *(const short8*)(Bb + ni * 2048);
      __builtin_amdgcn_s_setprio(1);
#pragma unroll
      for (int mi = 0; mi < 8; ++mi)
#pragma unroll
        for (int ni = 0; ni < 4; ++ni)
          acc[mi][ni] =
              __builtin_amdgcn_mfma_f32_16x16x32_bf16(af[mi], bfr[ni], acc[mi][ni], 0, 0, 0);
      __builtin_amdgcn_s_setprio(0);
    }
    {  // ks = 1
      const char* Ab = Asb + (aoff ^ 64u);
      const char* Bb = Bsb + (boff ^ 64u);
      short8 af[8], bfr[4];
#pragma unroll
      for (int mi = 0; mi < 8; ++mi) af[mi] = *(const short8*)(Ab + mi * 2048);
#pragma unroll
      for (int ni = 0; ni < 4; ++ni) bfr[ni] = *(const short8*)(Bb + ni * 2048);
      asm volatile("s_waitcnt lgkmcnt(0)" ::: "memory"); // this wave's reads done
      __builtin_amdgcn_s_barrier();                      // bar2: ALL waves' reads done
      __builtin_amdgcn_sched_barrier(0);                 // pin: no motion across
      if (kt + 2 < NT) stage(kt + 2, kt & 1);            // overwrite just-read buf
      __builtin_amdgcn_s_setprio(1);
#pragma unroll
      for (int mi = 0; mi < 8; ++mi)
#pragma unroll
        for (int ni = 0; ni < 4; ++ni)
          acc[mi][ni] =
              __builtin_amdgcn_mfma_f32_16x16x32_bf16(af[mi], bfr[ni], acc[mi][ni], 0, 0, 0);
      __builtin_amdgcn_s_setprio(0);
    }
  }
  // epilogue: gelu(acc + bias) -> bf16
#pragma unroll
  for (int mi = 0; mi < 8; ++mi)
#pragma unroll
    for (int ni = 0; ni < 4; ++ni) {
      long col = n0 + wn * 64 + ni * 16 + l15;
      float bv = bias[col];
#pragma unroll
      for (int r = 0; r < 4; ++r) {
        long row = m0 + wm * 128 + mi * 16 + quad * 4 + r;
        out_bf[row * (long)N + col] = f2bf(gelu_fast(acc[mi][ni][r] + bv));
      }
    }
}

extern "C" void kernel_launch(void* const* d_in, const int* in_sizes, int n_in,
                              void* d_out, int out_size, void* d_ws, size_t ws_size,
                              hipStream_t stream) {
  (void)in_sizes; (void)n_in; (void)out_size; (void)ws_size;
  const float* x   = (const float*)d_in[0];
  const float* Wq  = (const float*)d_in[1];
  const float* Wk  = (const float*)d_in[2];
  const float* Wv  = (const float*)d_in[3];
  const float* Wo  = (const float*)d_in[4];
  const float* bo  = (const float*)d_in[5];
  const float* l1g = (const float*)d_in[6];
  const float* l1b = (const float*)d_in[7];
  const float* l2g = (const float*)d_in[8];
  const float* l2b = (const float*)d_in[9];
  const float* W1  = (const float*)d_in[10];
  const float* b1  = (const float*)d_in[11];
  const float* W2  = (const float*)d_in[12];
  const float* b2  = (const float*)d_in[13];
  float* out = (float*)d_out;

  char* ws = (char*)d_ws;
  const size_t MB = 1ull << 20;
  ushort_t* XN  = (ushort_t*)(ws);            // 16MB [0,16)  ; reused as CTX
  ushort_t* Q   = (ushort_t*)(ws + 16 * MB);  // 16MB [16,32)
  ushort_t* Kb  = (ushort_t*)(ws + 32 * MB);  // 16MB [32,48)
  ushort_t* Vb  = (ushort_t*)(ws + 48 * MB);  // 16MB [48,64)
  float*    AO  = (float*)(ws + 64 * MB);     // 32MB [64,96)
  ushort_t* CTX = XN;
  ushort_t* AN  = (ushort_t*)(ws + 96 * MB);  // 16MB [96,112)
  ushort_t* FF1 = (ushort_t*)(ws);            // 64MB [0,64) over XN/Q/K/V (dead)
  ushort_t* WoT = (ushort_t*)(ws + 112 * MB); // 2MB
  ushort_t* W1T = (ushort_t*)(ws + 114 * MB); // 8MB
  ushort_t* W2T = (ushort_t*)(ws + 122 * MB); // 8MB
  ushort_t* WqT = (ushort_t*)(ws + 130 * MB);
  ushort_t* WkT = WqT + 4096;
  ushort_t* WvT = WkT + 4096;                 // total < 131MB

  dim3 b256(256);
  transpose_cast_k<<<dim3(2, 2), b256, 0, stream>>>(Wq, WqT, 64, 64);
  transpose_cast_k<<<dim3(2, 2), b256, 0, stream>>>(Wk, WkT, 64, 64);
  transpose_cast_k<<<dim3(2, 2), b256, 0, stream>>>(Wv, WvT, 64, 64);
  transpose_cast_k<<<dim3(32, 32), b256, 0, stream>>>(Wo, WoT, 1024, 1024);
  transpose_cast_k<<<dim3(128, 32), b256, 0, stream>>>(W1, W1T, 1024, 4096);
  transpose_cast_k<<<dim3(32, 128), b256, 0, stream>>>(W2, W2T, 4096, 1024);

  ln_k<<<dim3(TOKENS), b256, 0, stream>>>(x, l1g, l1b, XN);
  qkv_k<<<dim3(1024), b256, 0, stream>>>(XN, WqT, WkT, WvT, Q, Kb, Vb);
  attn_k<<<dim3(16, 64), b256, 0, stream>>>(Q, Kb, Vb, CTX);
  gemm_res256<<<dim3(8, 32), dim3(512), 0, stream>>>(CTX, WoT, bo, x, AO,
                                                     TOKENS, EMBED, EMBED);
  ln_k<<<dim3(TOKENS), b256, 0, stream>>>(AO, l2g, l2b, AN);
  gemm_ff1<<<dim3(16, 32), dim3(512), 0, stream>>>(AN, W1T, b1, FF1,
                                                   TOKENS, 4096, EMBED);
  gemm_res256<<<dim3(8, 32), dim3(512), 0, stream>>>(FF1, W2T, b2, AO, out,
                                                     TOKENS, EMBED, 4096);
}

// Round 13
// 456.613 us; speedup vs baseline: 1.0263x; 1.0263x over previous
//
#include <hip/hip_runtime.h>
#include <hip/hip_bf16.h>
#include <cstdint>
#include <math.h>

#define EMBED 1024
#define HEADS 16
#define HDIM 64
#define SEQ 2048
#define TOKENS 8192   // 4*2048

typedef __attribute__((ext_vector_type(8))) short short8;
typedef __attribute__((ext_vector_type(4))) float f32x4;
typedef __attribute__((ext_vector_type(2))) unsigned int uint2v;
typedef unsigned short ushort_t;

__device__ __forceinline__ float bf2f(ushort_t u) {
  union { unsigned int i; float f; } c; c.i = ((unsigned int)u) << 16; return c.f;
}
__device__ __forceinline__ ushort_t f2bf(float f) {
  union { float f; unsigned int i; } c; c.f = f;
  unsigned int x = c.i;
  unsigned int r = x + 0x7fffu + ((x >> 16) & 1u);  // RNE
  return (ushort_t)(r >> 16);
}
// pack two f32 -> two bf16 (round-half-up) in one dword: {hi=b, lo=a}
__device__ __forceinline__ unsigned int pack_bf16_rhu(float a, float b) {
  unsigned int ua = __float_as_uint(a) + 0x8000u;
  unsigned int ub = __float_as_uint(b) + 0x8000u;
  return __builtin_amdgcn_perm(ub, ua, 0x07060302u);
}
// single-instruction packed cvt (RNE): dst.lo = bf16(lo), dst.hi = bf16(hi)
__device__ __forceinline__ unsigned int cvt_pk_bf16(float lo, float hi) {
  unsigned int r;
  asm("v_cvt_pk_bf16_f32 %0, %1, %2" : "=v"(r) : "v"(lo), "v"(hi));
  return r;
}
__device__ __forceinline__ void g2lds16(const void* g, void* l) {
  __builtin_amdgcn_global_load_lds(
      (const __attribute__((address_space(1))) unsigned int*)g,
      (__attribute__((address_space(3))) unsigned int*)l, 16, 0, 0);
}
// exact-GELU via branchless A&S 7.1.26 erf (|eps|<=1.5e-7, way below bf16 ulp)
__device__ __forceinline__ float gelu_fast(float v) {
  float x = v * 0.70710678118654752f;          // v/sqrt(2)
  float ax = fabsf(x);
  float t = __builtin_amdgcn_rcpf(__builtin_fmaf(0.3275911f, ax, 1.0f));
  float p = __builtin_fmaf(1.061405429f, t, -1.453152027f);
  p = __builtin_fmaf(p, t, 1.421413741f);
  p = __builtin_fmaf(p, t, -0.284496736f);
  p = __builtin_fmaf(p, t, 0.254829592f);
  p = p * t;
  float e = __builtin_amdgcn_exp2f(-ax * ax * 1.4426950408889634f);
  float erfax = __builtin_fmaf(-p, e, 1.0f);   // erf(|x|)
  float erfx = copysignf(erfax, x);
  return 0.5f * v * (1.0f + erfx);
}

// ---------- prep: transpose + cast f32 -> bf16: out[c][r] = bf16(in[r][c]) --
__global__ __launch_bounds__(256) void transpose_cast_k(const float* __restrict__ in,
                                                        ushort_t* __restrict__ out,
                                                        int R, int C) {
  __shared__ ushort_t tile[32][33];
  int tx = threadIdx.x & 31, ty = threadIdx.x >> 5;
  int c0 = blockIdx.x * 32, r0 = blockIdx.y * 32;
#pragma unroll
  for (int i = ty; i < 32; i += 8)
    tile[i][tx] = f2bf(in[(long)(r0 + i) * C + (c0 + tx)]);
  __syncthreads();
#pragma unroll
  for (int i = ty; i < 32; i += 8) out[(long)(c0 + i) * R + (r0 + tx)] = tile[tx][i];
}

// ---------- layernorm rows of 1024, f32 in -> bf16 out ----------
// Output packed via v_cvt_pk_bf16_f32 (RNE, bit-identical to f2bf) into a
// single 8B store per thread (verified round 11, part of the 457.9us best).
__global__ __launch_bounds__(256) void ln_k(const float* __restrict__ xin,
                                            const float* __restrict__ g,
                                            const float* __restrict__ b,
                                            ushort_t* __restrict__ out) {
  int row = blockIdx.x, t = threadIdx.x;
  long base = (long)row * EMBED + t * 4;
  f32x4 xv = *(const f32x4*)(xin + base);
  float v[4] = {xv[0], xv[1], xv[2], xv[3]};
  float s1 = v[0] + v[1] + v[2] + v[3];
  float s2 = v[0]*v[0] + v[1]*v[1] + v[2]*v[2] + v[3]*v[3];
#pragma unroll
  for (int m = 1; m < 64; m <<= 1) { s1 += __shfl_xor(s1, m, 64); s2 += __shfl_xor(s2, m, 64); }
  __shared__ float ws1[4], ws2[4];
  int w = t >> 6, lane = t & 63;
  if (lane == 0) { ws1[w] = s1; ws2[w] = s2; }
  __syncthreads();
  float S1 = ws1[0] + ws1[1] + ws1[2] + ws1[3];
  float S2 = ws2[0] + ws2[1] + ws2[2] + ws2[3];
  float mean = S1 * (1.0f / EMBED);
  float var = S2 * (1.0f / EMBED) - mean * mean;
  float rstd = rsqrtf(var + 1e-5f);
  int c = t * 4;
  float y0 = (v[0] - mean) * rstd * g[c + 0] + b[c + 0];
  float y1 = (v[1] - mean) * rstd * g[c + 1] + b[c + 1];
  float y2 = (v[2] - mean) * rstd * g[c + 2] + b[c + 2];
  float y3 = (v[3] - mean) * rstd * g[c + 3] + b[c + 3];
  uint2v d;
  d[0] = cvt_pk_bf16(y0, y1);
  d[1] = cvt_pk_bf16(y2, y3);
  *(uint2v*)(out + (long)row * EMBED + c) = d;
}

// ---------------- fused QKV: [131072,64] x (64x64)^T x3 ----------------
// Q output is pre-scaled by log2(e)/sqrt(EMBED) so attention works directly in
// the exp2 domain. A-tile LDS is XOR-swizzled (chunk ^= row&7) via pre-swizzled
// global source (rule #21): linear g2lds dest + swizzled ds_read.
__global__ __launch_bounds__(256) void qkv_k(const ushort_t* __restrict__ xn,
                                             const ushort_t* __restrict__ WqT,
                                             const ushort_t* __restrict__ WkT,
                                             const ushort_t* __restrict__ WvT,
                                             ushort_t* __restrict__ q, ushort_t* __restrict__ k,
                                             ushort_t* __restrict__ v) {
  __shared__ __align__(16) ushort_t As[128 * 64];  // 16KB
  int t = threadIdx.x;
  long rowbase = (long)blockIdx.x * 128;
#pragma unroll
  for (int p = 0; p < 4; ++p) {
    int idx = p * 256 + t;             // 1024 chunks of 16B
    int row = idx >> 3, chunk = idx & 7;
    int sc = chunk ^ (row & 7);
    g2lds16(xn + (rowbase + row) * 64 + sc * 8, As + idx * 8);
  }
  __syncthreads();
  int w = t >> 6, lane = t & 63, l15 = lane & 15, quad = lane >> 4;
  short8 af[2][2];
#pragma unroll
  for (int mi = 0; mi < 2; ++mi)
#pragma unroll
    for (int ks = 0; ks < 2; ++ks) {
      int row = w * 32 + mi * 16 + l15;
      int ch = (ks * 4 + quad) ^ (row & 7);
      af[mi][ks] = *(const short8*)(As + row * 64 + ch * 8);
    }
  const ushort_t* Ws[3] = {WqT, WkT, WvT};
  ushort_t* Os[3] = {q, k, v};
#pragma unroll
  for (int wsel = 0; wsel < 3; ++wsel) {
    const ushort_t* W = Ws[wsel];
    float oscale = (wsel == 0) ? 0.0450842200277801f : 1.0f;  // log2e/32 : 1
    short8 bfr[4][2];
#pragma unroll
    for (int ni = 0; ni < 4; ++ni)
#pragma unroll
      for (int ks = 0; ks < 2; ++ks)
        bfr[ni][ks] = *(const short8*)(W + (ni * 16 + l15) * 64 + ks * 32 + quad * 8);
    f32x4 acc[2][4] = {};
#pragma unroll
    for (int mi = 0; mi < 2; ++mi)
#pragma unroll
      for (int ni = 0; ni < 4; ++ni)
#pragma unroll
        for (int ks = 0; ks < 2; ++ks)
          acc[mi][ni] = __builtin_amdgcn_mfma_f32_16x16x32_bf16(af[mi][ks], bfr[ni][ks],
                                                                acc[mi][ni], 0, 0, 0);
    ushort_t* O = Os[wsel];
#pragma unroll
    for (int mi = 0; mi < 2; ++mi)
#pragma unroll
      for (int ni = 0; ni < 4; ++ni)
#pragma unroll
        for (int r = 0; r < 4; ++r) {
          long rg = rowbase + w * 32 + mi * 16 + quad * 4 + r;
          O[rg * 64 + ni * 16 + l15] = f2bf(acc[mi][ni][r] * oscale);
        }
  }
}

// ---------------- flash attention: grid (16 qtiles, 64 batch-heads) ---------
// Round-5/7 structure (measured 105.1-106.7 five times). LOCAL OPTIMUM —
// do not restructure.
#define KSTR 72
__global__ __launch_bounds__(256, 4) void attn_k(const ushort_t* __restrict__ q,
                                                 const ushort_t* __restrict__ kk,
                                                 const ushort_t* __restrict__ vv,
                                                 ushort_t* __restrict__ ctx) {
  __shared__ __align__(16) ushort_t sm[64 * KSTR * 2];
  ushort_t* Ks = sm;                    // [key][KSTR]
  ushort_t* Vt = sm + 64 * KSTR;        // [d][KSTR], key-permuted columns
  int t = threadIdx.x;
  int nb = gridDim.x * gridDim.y;                      // 1024, %8==0
  int bid = blockIdx.x + gridDim.x * blockIdx.y;
  int swz = (bid & 7) * (nb >> 3) + (bid >> 3);
  int qt = swz & (gridDim.x - 1), bh = swz / gridDim.x;
  int n = bh >> 4, h = bh & 15;
  long qtok0 = (long)n * SEQ + qt * 128;
  int w = t >> 6, lane = t & 63, l15 = lane & 15, quad = lane >> 4;
  short8 qf[2][2];
#pragma unroll
  for (int g = 0; g < 2; ++g)
#pragma unroll
    for (int ks = 0; ks < 2; ++ks)
      qf[g][ks] = *(const short8*)(q + (qtok0 + w * 32 + g * 16 + l15) * EMBED +
                                   h * HDIM + ks * 32 + quad * 8);
  short8 ones;
#pragma unroll
  for (int j = 0; j < 8; ++j) ones[j] = (short)0x3F80;  // bf16 1.0
  int vkey = t & 63;
  int vcol = (vkey & 32) | ((vkey & 12) << 1) | ((vkey & 16) >> 2) | (vkey & 3);
  const ushort_t* kp = kk + ((long)n * SEQ + (t >> 3)) * EMBED + h * HDIM + (t & 7) * 8;
  const ushort_t* vp = vv + ((long)n * SEQ + vkey) * EMBED + h * HDIM + w * 8;
  float m_run[2] = {-1e30f, -1e30f}, l_run[2] = {0.f, 0.f};
  f32x4 acc_o[2][4] = {};   // O^T per group: d = nf*16+quad*4+r, q = l15
  for (int kt = 0; kt < SEQ / 64; ++kt) {
    short8 kreg[2];
#pragma unroll
    for (int p = 0; p < 2; ++p) kreg[p] = *(const short8*)(kp + (long)p * 32 * EMBED);
    short8 vreg[2];
#pragma unroll
    for (int p = 0; p < 2; ++p) vreg[p] = *(const short8*)(vp + p * 32);
    kp += 64 * EMBED;
    vp += 64 * EMBED;
    __syncthreads();  // previous tile's readers done
#pragma unroll
    for (int p = 0; p < 2; ++p) {
      int idx = p * 256 + t;
      int key = idx >> 3, chunk = idx & 7;
      *(short8*)(Ks + key * KSTR + chunk * 8) = kreg[p];
    }
#pragma unroll
    for (int p = 0; p < 2; ++p) {
      int c = p * 4 + w;
#pragma unroll
      for (int j = 0; j < 8; ++j) Vt[(c * 8 + j) * KSTR + vcol] = (ushort_t)vreg[p][j];
    }
    __syncthreads();
    // S^T[key][q] = mfma(A=K, B=Q): K fragments shared by both q-groups
    f32x4 st[2][4] = {};
#pragma unroll
    for (int ks = 0; ks < 2; ++ks)
#pragma unroll
      for (int nf = 0; nf < 4; ++nf) {
        short8 kf = *(const short8*)(Ks + (nf * 16 + l15) * KSTR + ks * 32 + quad * 8);
        st[0][nf] = __builtin_amdgcn_mfma_f32_16x16x32_bf16(kf, qf[0][ks], st[0][nf], 0, 0, 0);
        st[1][nf] = __builtin_amdgcn_mfma_f32_16x16x32_bf16(kf, qf[1][ks], st[1][nf], 0, 0, 0);
      }
    unsigned int Dk[2][4][2];
    float alpha[2];
#pragma unroll
    for (int g = 0; g < 2; ++g) {
      float mx = fmaxf(fmaxf(st[g][0][0], st[g][0][1]), fmaxf(st[g][0][2], st[g][0][3]));
#pragma unroll
      for (int nf = 1; nf < 4; ++nf)
        mx = fmaxf(mx, fmaxf(fmaxf(st[g][nf][0], st[g][nf][1]),
                             fmaxf(st[g][nf][2], st[g][nf][3])));
      mx = fmaxf(mx, __shfl_xor(mx, 16, 64));
      mx = fmaxf(mx, __shfl_xor(mx, 32, 64));
      float mold = m_run[g];
      int skip = __all(mx - mold <= 8.0f);
      float mnew = skip ? mold : fmaxf(mold, mx);
      alpha[g] = skip ? 1.0f : __builtin_amdgcn_exp2f(mold - mnew);
      m_run[g] = mnew;
#pragma unroll
      for (int nf = 0; nf < 4; ++nf) {
#pragma unroll
        for (int r = 0; r < 4; ++r)
          st[g][nf][r] = __builtin_amdgcn_exp2f(st[g][nf][r] - mnew);
        Dk[g][nf][0] = cvt_pk_bf16(st[g][nf][0], st[g][nf][1]);
        Dk[g][nf][1] = cvt_pk_bf16(st[g][nf][2], st[g][nf][3]);
      }
      if (!skip) {
#pragma unroll
        for (int nf = 0; nf < 4; ++nf)
#pragma unroll
          for (int r = 0; r < 4; ++r) acc_o[g][nf][r] *= alpha[g];
      }
    }
    f32x4 ts[2] = {};
#pragma unroll
    for (int ks = 0; ks < 2; ++ks) {
      union { unsigned int u[4]; short8 s8; } pf0, pf1;
      pf0.u[0] = Dk[0][2 * ks][0];     pf0.u[1] = Dk[0][2 * ks][1];
      pf0.u[2] = Dk[0][2 * ks + 1][0]; pf0.u[3] = Dk[0][2 * ks + 1][1];
      pf1.u[0] = Dk[1][2 * ks][0];     pf1.u[1] = Dk[1][2 * ks][1];
      pf1.u[2] = Dk[1][2 * ks + 1][0]; pf1.u[3] = Dk[1][2 * ks + 1][1];
      ts[0] = __builtin_amdgcn_mfma_f32_16x16x32_bf16(ones, pf0.s8, ts[0], 0, 0, 0);
      ts[1] = __builtin_amdgcn_mfma_f32_16x16x32_bf16(ones, pf1.s8, ts[1], 0, 0, 0);
#pragma unroll
      for (int nf = 0; nf < 4; ++nf) {
        short8 vf = *(const short8*)(Vt + (nf * 16 + l15) * KSTR + ks * 32 + quad * 8);
        acc_o[0][nf] = __builtin_amdgcn_mfma_f32_16x16x32_bf16(vf, pf0.s8, acc_o[0][nf], 0, 0, 0);
        acc_o[1][nf] = __builtin_amdgcn_mfma_f32_16x16x32_bf16(vf, pf1.s8, acc_o[1][nf], 0, 0, 0);
      }
    }
    l_run[0] = l_run[0] * alpha[0] + ts[0][0];
    l_run[1] = l_run[1] * alpha[1] + ts[1][0];
  }
#pragma unroll
  for (int g = 0; g < 2; ++g) {
    float inv_l = 1.0f / fmaxf(l_run[g], 1e-30f);
    long tok = qtok0 + w * 32 + g * 16 + l15;
#pragma unroll
    for (int nf = 0; nf < 4; ++nf) {
      unsigned int d0 = pack_bf16_rhu(acc_o[g][nf][0] * inv_l, acc_o[g][nf][1] * inv_l);
      unsigned int d1 = pack_bf16_rhu(acc_o[g][nf][2] * inv_l, acc_o[g][nf][3] * inv_l);
      unsigned int* dst = (unsigned int*)(ctx + tok * EMBED + h * HDIM + nf * 16 + quad * 4);
      dst[0] = d0;
      dst[1] = d1;
    }
  }
}

// ---------------- gemm_res256: 256x128, BK=64, 8-wave deep pipeline ---------
// REVERT to the round-9/11 swz mapping (part of the measured-best 457.9us
// config). The round-12 XCD-region remap coincided with a +10.7us total
// regression while ff1 (the only other change) improved — not validated.
__global__ __launch_bounds__(512, 2) void gemm_res256(const ushort_t* __restrict__ A,
                                                      const ushort_t* __restrict__ BT,
                                                      const float* __restrict__ bias,
                                                      const float* __restrict__ res,
                                                      float* __restrict__ out_f,
                                                      int M, int N, int K) {
  __shared__ __align__(16) ushort_t As[2][256 * 64];   // 64KB
  __shared__ __align__(16) ushort_t Bs[2][128 * 64];   // 32KB
  int t = threadIdx.x;
  int nbx = gridDim.x;                 // 8 N-tiles
  int nb = nbx * gridDim.y;            // 256, %8==0
  int bid = blockIdx.x + nbx * blockIdx.y;
  int swz = (bid & 7) * (nb >> 3) + (bid >> 3);
  int by = swz / nbx, bx = swz - by * nbx;
  long m0 = (long)by * 256;
  long n0 = (long)bx * 128;
  int w = t >> 6, lane = t & 63, l15 = lane & 15, quad = lane >> 4;
  int wm = w >> 2, wn = w & 3;         // 2 x 4 wave grid, 128x32 per wave
  int r0 = t >> 3;                     // 0..63
  int sc = (t & 7) ^ (r0 & 7);         // p*64 ≡ 0 mod 8 -> p-invariant
  const ushort_t* ap = A + (m0 + r0) * (long)K + sc * 8;
  const ushort_t* bp = BT + (n0 + r0) * (long)K + sc * 8;
  long pstride = (long)64 * K;
  int NT = K >> 6;
  auto stage = [&](int kt, int buf) {
    const ushort_t* a = ap + (long)kt * 64;
    const ushort_t* b = bp + (long)kt * 64;
#pragma unroll
    for (int p = 0; p < 4; ++p)        // A: 256 rows = 4 passes of 64
      g2lds16(a + p * pstride, As[buf] + (p * 512 + t) * 8);
#pragma unroll
    for (int p = 0; p < 2; ++p)        // B: 128 rows = 2 passes of 64
      g2lds16(b + p * pstride, Bs[buf] + (p * 512 + t) * 8);
  };
  unsigned cb = (unsigned)((quad ^ (l15 & 7)) * 16);
  unsigned aoff = (unsigned)((wm * 128 + l15) * 128) + cb;
  unsigned boff = (unsigned)((wn * 32 + l15) * 128) + cb;
  f32x4 acc[8][2] = {};
  stage(0, 0);
  stage(1, 1);
  for (int kt = 0; kt < NT; ++kt) {
    if (kt + 1 < NT) {
      asm volatile("s_waitcnt vmcnt(6)" ::: "memory");   // tile kt's 6 landed
    } else {
      asm volatile("s_waitcnt vmcnt(0)" ::: "memory");   // final drain
    }
    __builtin_amdgcn_s_barrier();                        // bar1
    const char* Asb = (const char*)As[kt & 1];
    const char* Bsb = (const char*)Bs[kt & 1];
    {  // ks = 0
      const char* Ab = Asb + aoff;
      const char* Bb = Bsb + boff;
      short8 af[8], bfr[2];
#pragma unroll
      for (int mi = 0; mi < 8; ++mi) af[mi] = *(const short8*)(Ab + mi * 2048);
#pragma unroll
      for (int ni = 0; ni < 2; ++ni) bfr[ni] = *(const short8*)(Bb + ni * 2048);
      __builtin_amdgcn_s_setprio(1);
#pragma unroll
      for (int mi = 0; mi < 8; ++mi)
#pragma unroll
        for (int ni = 0; ni < 2; ++ni)
          acc[mi][ni] =
              __builtin_amdgcn_mfma_f32_16x16x32_bf16(af[mi], bfr[ni], acc[mi][ni], 0, 0, 0);
      __builtin_amdgcn_s_setprio(0);
    }
    {  // ks = 1
      const char* Ab = Asb + (aoff ^ 64u);
      const char* Bb = Bsb + (boff ^ 64u);
      short8 af[8], bfr[2];
#pragma unroll
      for (int mi = 0; mi < 8; ++mi) af[mi] = *(const short8*)(Ab + mi * 2048);
#pragma unroll
      for (int ni = 0; ni < 2; ++ni) bfr[ni] = *(const short8*)(Bb + ni * 2048);
      asm volatile("s_waitcnt lgkmcnt(0)" ::: "memory"); // this wave's reads done
      __builtin_amdgcn_s_barrier();                      // bar2: ALL waves done
      __builtin_amdgcn_sched_barrier(0);                 // pin: no motion across
      if (kt + 2 < NT) stage(kt + 2, kt & 1);            // restage just-read buf
      __builtin_amdgcn_s_setprio(1);
#pragma unroll
      for (int mi = 0; mi < 8; ++mi)
#pragma unroll
        for (int ni = 0; ni < 2; ++ni)
          acc[mi][ni] =
              __builtin_amdgcn_mfma_f32_16x16x32_bf16(af[mi], bfr[ni], acc[mi][ni], 0, 0, 0);
      __builtin_amdgcn_s_setprio(0);
    }
  }
  // epilogue: acc + bias + res -> f32
#pragma unroll
  for (int mi = 0; mi < 8; ++mi)
#pragma unroll
    for (int ni = 0; ni < 2; ++ni) {
      long col = n0 + wn * 32 + ni * 16 + l15;
      float bv = bias[col];
#pragma unroll
      for (int r = 0; r < 4; ++r) {
        long row = m0 + wm * 128 + mi * 16 + quad * 4 + r;
        long off = row * (long)N + col;
        out_f[off] = acc[mi][ni][r] + bv + res[off];
      }
    }
}

// ---------------- gemm_ff1: 256x256, BK=64, 8-wave deep pipeline ------------
// Round-7 coarse 2-block schedule + round-12 XCD-tiled mapping (KEPT:
// within-kernel A/B showed FETCH 74->49MB, dur 124.7->121.2us).
__global__ __launch_bounds__(512, 2) void gemm_ff1(const ushort_t* __restrict__ A,
                                                   const ushort_t* __restrict__ BT,
                                                   const float* __restrict__ bias,
                                                   ushort_t* __restrict__ out_bf,
                                                   int M, int N, int K) {
  __shared__ __align__(16) ushort_t As[2][256 * 64];   // 64KB
  __shared__ __align__(16) ushort_t Bs[2][256 * 64];   // 64KB
  int t = threadIdx.x;
  int nbx = gridDim.x;                 // 16 N-tiles
  int bid = blockIdx.x + nbx * blockIdx.y;   // 0..511
  // XCD-tiled mapping: grid (32 M x 16 N) split into 4x2 regions of 8M x 8N,
  // one region per XCD (bid&7 ~ XCD). B per XCD = 8 panels = 4MB (fits L2).
  int xcd = bid & 7, l = bid >> 3;     // l in 0..63
  int by = (xcd >> 1) * 8 + (l >> 3);
  int bx = (xcd & 1) * 8 + (l & 7);
  long m0 = (long)by * 256;
  long n0 = (long)bx * 256;
  int w = t >> 6, lane = t & 63, l15 = lane & 15, quad = lane >> 4;
  int wm = w >> 2, wn = w & 3;         // 2 x 4 wave grid, 128x64 per wave
  int r0 = t >> 3;                     // 0..63
  int sc = (t & 7) ^ (r0 & 7);         // p*64 ≡ 0 mod 8 -> p-invariant
  const ushort_t* ap = A + (m0 + r0) * (long)K + sc * 8;
  const ushort_t* bp = BT + (n0 + r0) * (long)K + sc * 8;
  long pstride = (long)64 * K;
  int NT = K >> 6;                     // 16
  auto stage = [&](int kt, int buf) {
    const ushort_t* a = ap + (long)kt * 64;
    const ushort_t* b = bp + (long)kt * 64;
#pragma unroll
    for (int p = 0; p < 4; ++p) {
      g2lds16(a + p * pstride, As[buf] + (p * 512 + t) * 8);
      g2lds16(b + p * pstride, Bs[buf] + (p * 512 + t) * 8);
    }
  };
  unsigned cb = (unsigned)((quad ^ (l15 & 7)) * 16);
  unsigned aoff = (unsigned)((wm * 128 + l15) * 128) + cb;
  unsigned boff = (unsigned)((wn * 64 + l15) * 128) + cb;
  f32x4 acc[8][4] = {};
  stage(0, 0);
  stage(1, 1);
  for (int kt = 0; kt < NT; ++kt) {
    if (kt + 1 < NT) {
      asm volatile("s_waitcnt vmcnt(8)" ::: "memory");   // tile kt landed
    } else {
      asm volatile("s_waitcnt vmcnt(0)" ::: "memory");   // final drain
    }
    __builtin_amdgcn_s_barrier();                        // bar1
    const char* Asb = (const char*)As[kt & 1];
    const char* Bsb = (const char*)Bs[kt & 1];
    {  // ks = 0
      const char* Ab = Asb + aoff;
      const char* Bb = Bsb + boff;
      short8 af[8], bfr[4];
#pragma unroll
      for (int mi = 0; mi < 8; ++mi) af[mi] = *(const short8*)(Ab + mi * 2048);
#pragma unroll
      for (int ni = 0; ni < 4; ++ni) bfr[ni] = *(const short8*)(Bb + ni * 2048);
      __builtin_amdgcn_s_setprio(1);
#pragma unroll
      for (int mi = 0; mi < 8; ++mi)
#pragma unroll
        for (int ni = 0; ni < 4; ++ni)
          acc[mi][ni] =
              __builtin_amdgcn_mfma_f32_16x16x32_bf16(af[mi], bfr[ni], acc[mi][ni], 0, 0, 0);
      __builtin_amdgcn_s_setprio(0);
    }
    {  // ks = 1
      const char* Ab = Asb + (aoff ^ 64u);
      const char* Bb = Bsb + (boff ^ 64u);
      short8 af[8], bfr[4];
#pragma unroll
      for (int mi = 0; mi < 8; ++mi) af[mi] = *(const short8*)(Ab + mi * 2048);
#pragma unroll
      for (int ni = 0; ni < 4; ++ni) bfr[ni] = *(const short8*)(Bb + ni * 2048);
      asm volatile("s_waitcnt lgkmcnt(0)" ::: "memory"); // this wave's reads done
      __builtin_amdgcn_s_barrier();                      // bar2: ALL waves' reads done
      __builtin_amdgcn_sched_barrier(0);                 // pin: no motion across
      if (kt + 2 < NT) stage(kt + 2, kt & 1);            // overwrite just-read buf
      __builtin_amdgcn_s_setprio(1);
#pragma unroll
      for (int mi = 0; mi < 8; ++mi)
#pragma unroll
        for (int ni = 0; ni < 4; ++ni)
          acc[mi][ni] =
              __builtin_amdgcn_mfma_f32_16x16x32_bf16(af[mi], bfr[ni], acc[mi][ni], 0, 0, 0);
      __builtin_amdgcn_s_setprio(0);
    }
  }
  // epilogue: gelu(acc + bias) -> bf16
#pragma unroll
  for (int mi = 0; mi < 8; ++mi)
#pragma unroll
    for (int ni = 0; ni < 4; ++ni) {
      long col = n0 + wn * 64 + ni * 16 + l15;
      float bv = bias[col];
#pragma unroll
      for (int r = 0; r < 4; ++r) {
        long row = m0 + wm * 128 + mi * 16 + quad * 4 + r;
        out_bf[row * (long)N + col] = f2bf(gelu_fast(acc[mi][ni][r] + bv));
      }
    }
}

extern "C" void kernel_launch(void* const* d_in, const int* in_sizes, int n_in,
                              void* d_out, int out_size, void* d_ws, size_t ws_size,
                              hipStream_t stream) {
  (void)in_sizes; (void)n_in; (void)out_size; (void)ws_size;
  const float* x   = (const float*)d_in[0];
  const float* Wq  = (const float*)d_in[1];
  const float* Wk  = (const float*)d_in[2];
  const float* Wv  = (const float*)d_in[3];
  const float* Wo  = (const float*)d_in[4];
  const float* bo  = (const float*)d_in[5];
  const float* l1g = (const float*)d_in[6];
  const float* l1b = (const float*)d_in[7];
  const float* l2g = (const float*)d_in[8];
  const float* l2b = (const float*)d_in[9];
  const float* W1  = (const float*)d_in[10];
  const float* b1  = (const float*)d_in[11];
  const float* W2  = (const float*)d_in[12];
  const float* b2  = (const float*)d_in[13];
  float* out = (float*)d_out;

  char* ws = (char*)d_ws;
  const size_t MB = 1ull << 20;
  ushort_t* XN  = (ushort_t*)(ws);            // 16MB [0,16)  ; reused as CTX
  ushort_t* Q   = (ushort_t*)(ws + 16 * MB);  // 16MB [16,32)
  ushort_t* Kb  = (ushort_t*)(ws + 32 * MB);  // 16MB [32,48)
  ushort_t* Vb  = (ushort_t*)(ws + 48 * MB);  // 16MB [48,64)
  float*    AO  = (float*)(ws + 64 * MB);     // 32MB [64,96)
  ushort_t* CTX = XN;
  ushort_t* AN  = (ushort_t*)(ws + 96 * MB);  // 16MB [96,112)
  ushort_t* FF1 = (ushort_t*)(ws);            // 64MB [0,64) over XN/Q/K/V (dead)
  ushort_t* WoT = (ushort_t*)(ws + 112 * MB); // 2MB
  ushort_t* W1T = (ushort_t*)(ws + 114 * MB); // 8MB
  ushort_t* W2T = (ushort_t*)(ws + 122 * MB); // 8MB
  ushort_t* WqT = (ushort_t*)(ws + 130 * MB);
  ushort_t* WkT = WqT + 4096;
  ushort_t* WvT = WkT + 4096;                 // total < 131MB

  dim3 b256(256);
  transpose_cast_k<<<dim3(2, 2), b256, 0, stream>>>(Wq, WqT, 64, 64);
  transpose_cast_k<<<dim3(2, 2), b256, 0, stream>>>(Wk, WkT, 64, 64);
  transpose_cast_k<<<dim3(2, 2), b256, 0, stream>>>(Wv, WvT, 64, 64);
  transpose_cast_k<<<dim3(32, 32), b256, 0, stream>>>(Wo, WoT, 1024, 1024);
  transpose_cast_k<<<dim3(128, 32), b256, 0, stream>>>(W1, W1T, 1024, 4096);
  transpose_cast_k<<<dim3(32, 128), b256, 0, stream>>>(W2, W2T, 4096, 1024);

  ln_k<<<dim3(TOKENS), b256, 0, stream>>>(x, l1g, l1b, XN);
  qkv_k<<<dim3(1024), b256, 0, stream>>>(XN, WqT, WkT, WvT, Q, Kb, Vb);
  attn_k<<<dim3(16, 64), b256, 0, stream>>>(Q, Kb, Vb, CTX);
  gemm_res256<<<dim3(8, 32), dim3(512), 0, stream>>>(CTX, WoT, bo, x, AO,
                                                     TOKENS, EMBED, EMBED);
  ln_k<<<dim3(TOKENS), b256, 0, stream>>>(AO, l2g, l2b, AN);
  gemm_ff1<<<dim3(16, 32), dim3(512), 0, stream>>>(AN, W1T, b1, FF1,
                                                   TOKENS, 4096, EMBED);
  gemm_res256<<<dim3(8, 32), dim3(512), 0, stream>>>(FF1, W2T, b2, AO, out,
                                                     TOKENS, EMBED, 4096);
}